// Round 1
// baseline (278.786 us; speedup 1.0000x reference)
//
#include <hip/hip_runtime.h>
#include <math.h>

// ForwardDiffusion: x_t = a*x_{t-1} + c*z_t, a = 1-THETA*DT, c = SIGMA0*sqrt(DT).
// Noise is batch-independent => closed form x_t[b,l] = a^t * x0[b,l] + c * S_t[l],
// S_t[l] = a*S_{t-1}[l] + z_t[l] (single (999,1024) scan, no per-batch scan).
//
// ws layout (floats): S[STEPS*LEN] | carry[NCHUNK*LEN] | apow[STEPS]
//
// R1 change: k_emit regrouped from (b,t) blocks (64000 blocks x 4KB writes,
// 48B read/16B write per thread) to (b,chunk) blocks: each block emits the 16
// chunk-aligned t-rows, so carry row is block-constant (hoisted), x is loaded
// once, and the block writes a contiguous 64-68KB region. L2 read traffic
// 786MB -> ~290MB; write stream becomes long contiguous bursts.

namespace {
constexpr int LEN    = 1024;
constexpr int BATCH  = 64;
constexpr int STEPS  = 1000;
constexpr int NST    = 999;
constexpr int CHUNK  = 16;
constexpr int NCHUNK = (NST + CHUNK - 1) / CHUNK;  // 63
constexpr float THETA = 1.0f;
constexpr float DT    = 0.001f;
typedef float f32x4 __attribute__((ext_vector_type(4)));
}

// Kernel 1: per-chunk local scans, carry-in 0. grid (NCHUNK, 4) x 256 threads:
// 252 blocks spread across CUs. Block (g, y) handles lanes [y*256, y*256+256)
// for t in [g*CHUNK+1, min((g+1)*CHUNK, NST)]. g==0 also zeroes the t=0 row.
__global__ __launch_bounds__(256) void k_partial(const float* __restrict__ noise,
                                                 float* __restrict__ S) {
    const int l = blockIdx.y * 256 + threadIdx.x;
    const int g = blockIdx.x;
    const float a = 1.0f - THETA * DT;
    if (g == 0) S[l] = 0.0f;
    const int t0 = g * CHUNK + 1;
    const int t1 = min((g + 1) * CHUNK, NST);
    float acc = 0.0f;
    #pragma unroll
    for (int t = t0; t <= t1; ++t) {
        acc = a * acc + noise[(t - 1) * LEN + l];
        S[t * LEN + l] = acc;
    }
}

// Kernel 2: combine chunk carries. grid (4) x 256 threads. The 63 S-loads are
// independent of the serial FMA chain -> prefetch all into registers first
// (latency paid once, not 63x). Also builds the a^t table.
__global__ __launch_bounds__(256) void k_combine(const float* __restrict__ S,
                                                 float* __restrict__ carry,
                                                 float* __restrict__ apow) {
    const int l = blockIdx.x * 256 + threadIdx.x;
    const float a = 1.0f - THETA * DT;
    if (l < STEPS) apow[l] = powf(a, (float)l);

    float vals[NCHUNK];
    #pragma unroll
    for (int g = 0; g < NCHUNK; ++g) {
        const int t1 = min((g + 1) * CHUNK, NST);
        vals[g] = S[t1 * LEN + l];           // independent loads, pipelined
    }
    // a^CHUNK; the last (short) chunk's carry-out is never consumed, so constant is safe.
    const float a16 = 0.98411684f;           // (1-0.001)^16
    float cr = 0.0f;
    #pragma unroll
    for (int g = 0; g < NCHUNK; ++g) {
        carry[g * LEN + l] = cr;
        cr = a16 * cr + vals[g];
    }
}

// Kernel 3: out[b][t][l] = a^t * x0[b,l] + c*S_loc[t][l] + (c*a^tloc)*carry[g][l].
// grid (BATCH, NCHUNK) x 256: block (b,g) emits t in [16g+1, 16g+16] (chunk-
// aligned, so carry row g is BLOCK-CONSTANT) plus t=0 for g==0. Per thread:
// x and c*carry hoisted to registers; 16 independent S loads + 16 contiguous
// nontemporal f32x4 stores (64KB contiguous per block). 64 consecutive blocks
// share the same 16 S rows + carry row -> tight L2 reuse window per XCD.
__global__ __launch_bounds__(256) void k_emit(const float* __restrict__ x0,
                                              const float* __restrict__ S,
                                              const float* __restrict__ carry,
                                              const float* __restrict__ apow,
                                              float* __restrict__ out) {
    const int b = blockIdx.x;
    const int g = blockIdx.y;
    const float c = 0.5f * sqrtf(DT);
    const int l4 = threadIdx.x;
    const f32x4 x   = ((const f32x4*)(x0 + b * LEN))[l4];
    const f32x4 ccr = c * ((const f32x4*)(carry + g * LEN))[l4];
    float* outb = out + (size_t)b * STEPS * LEN;

    if (g == 0) {
        // t = 0: apow[0]=1, S row 0 is zeros, carry row 0 is zeros -> out = x.
        __builtin_nontemporal_store(x, (f32x4*)outb + l4);
    }
    const int tbase = g * CHUNK;

    auto emit1 = [&](int i) {
        const int t = tbase + i;
        const float ap  = apow[t];           // uniform scalar loads (L1-resident)
        const float apl = apow[i];
        const f32x4 s = ((const f32x4*)(S + t * LEN))[l4];
        f32x4 o = ap * x + c * s + apl * ccr;
        __builtin_nontemporal_store(o, (f32x4*)(outb + (size_t)t * LEN) + l4);
    };

    if (tbase + CHUNK <= NST) {              // full chunk: g = 0..61
        #pragma unroll
        for (int i = 1; i <= CHUNK; ++i) emit1(i);
    } else {                                 // g = 62: t = 993..999 (7 rows)
        #pragma unroll
        for (int i = 1; i <= NST - (NCHUNK - 1) * CHUNK; ++i) emit1(i);
    }
}

extern "C" void kernel_launch(void* const* d_in, const int* in_sizes, int n_in,
                              void* d_out, int out_size, void* d_ws, size_t ws_size,
                              hipStream_t stream) {
    const float* x     = (const float*)d_in[0];   // (64, 1024) fp32
    const float* noise = (const float*)d_in[1];   // (999, 1024) fp32
    float* out = (float*)d_out;                   // (64, 1000, 1024) fp32
    float* ws  = (float*)d_ws;

    float* S     = ws;                      // STEPS*LEN
    float* carry = S + STEPS * LEN;         // NCHUNK*LEN
    float* apow  = carry + NCHUNK * LEN;    // STEPS

    hipLaunchKernelGGL(k_partial, dim3(NCHUNK, 4), dim3(256), 0, stream, noise, S);
    hipLaunchKernelGGL(k_combine, dim3(4), dim3(256), 0, stream, S, carry, apow);
    hipLaunchKernelGGL(k_emit, dim3(BATCH, NCHUNK), dim3(256), 0, stream,
                       x, S, carry, apow, out);
}